// Round 4
// baseline (784.798 us; speedup 1.0000x reference)
//
#include <hip/hip_runtime.h>
#include <hip/hip_bf16.h>
#include <stdint.h>
#include <stddef.h>

typedef __bf16 bf16_t;
typedef __bf16 bf16x8 __attribute__((ext_vector_type(8)));
typedef __bf16 bf16x4 __attribute__((ext_vector_type(4)));
typedef float  f32x4  __attribute__((ext_vector_type(4)));

#define MFMA16(a, b, c) __builtin_amdgcn_mfma_f32_16x16x32_bf16((a), (b), (c), 0, 0, 0)

// SiLU with raw v_rcp_f32 (1-ulp; invisible after bf16 truncation) instead of
// the exact-division div_scale/div_fmas/div_fixup sequence (~10 VALU ops).
__device__ __forceinline__ float silu_f(float v) {
    return v * __builtin_amdgcn_rcpf(1.f + __expf(-v));
}

namespace cfg {
constexpr int B    = 131072;
constexpr int DIM  = 40;
constexpr int H    = 128;
constexpr int AD   = 20;
constexpr int L    = 6;
constexpr int MB   = 64;     // rows per block
constexpr int NTH  = 256;    // threads per block (4 waves)

// uniform transposed-weight tiles: [L][21][128][32] bf16 (64-B rows, line-aligned)
//   tiles 0..8  = W1 K-tiles (K padded 288)
//   tiles 9..12 = W2, 13..16 = W3, 17..20 = [Ws|Wt] (cols 0..19 s, 32..51 t)
constexpr int TILE = 128 * 32;      // 4096 elems / 8192 B
constexpr int LSTR = 21 * TILE;     // per-layer stride
constexpr int WTOT = 6 * LSTR;      // 516096 elems
}

// Static module-scope staging; rewritten by prep kernels every launch.
__device__ bf16_t g_wsb[cfg::WTOT];
// physical-slot tables: pa[6][32] (k 20..31 padded w/ slot 0), pb[6][20], fout[40]
__device__ int    g_gtab[352];
__device__ bf16_t g_cte[(size_t)cfg::B * 256];   // [B][ctx(128)|te(128)] bf16

// ---------------------------------------------------------------------------
// prep_w: fp32 weights -> bf16 transposed tiles [n(128)][k(32)].
// Block 0 additionally composes the permutation algebra into physical-slot
// tables:  value of logical z_i[d] lives at fixed physical slot phys_i[d];
// y_b overwrites the slot its z_b came from, z_a never moves.
// ---------------------------------------------------------------------------
__global__ void prep_w(const float* __restrict__ W1, const float* __restrict__ W2,
                       const float* __restrict__ W3, const float* __restrict__ Ws,
                       const float* __restrict__ Wt, const int* __restrict__ perm,
                       const int* __restrict__ ia, const int* __restrict__ ib)
{
    using namespace cfg;
    __shared__ int phys_s[40], tmp_s[40], pas[20], pbs[20];

    int t = blockIdx.x * blockDim.x + threadIdx.x;
    if (t < WTOT) {
        int i = t / LSTR, r = t % LSTR;
        int tile = r / TILE, r2 = r % TILE;
        int n = r2 >> 5, kl = r2 & 31;
        float v = 0.f;
        if (tile < 9) {                      // W1: h0 k-layout [za(20) pad12 | ctx | te]
            int k = tile * 32 + kl;
            if (k < 20)       v = W1[(i * 276 + k) * 128 + n];
            else if (k >= 32) v = W1[(i * 276 + (k - 12)) * 128 + n];
        } else if (tile < 13) {
            int k = (tile - 9) * 32 + kl;
            v = W2[(i * 128 + k) * 128 + n];
        } else if (tile < 17) {
            int k = (tile - 13) * 32 + kl;
            v = W3[(i * 128 + k) * 128 + n];
        } else {
            int k = (tile - 17) * 32 + kl;
            if (n < 20)                 v = Ws[(i * 128 + k) * 20 + n];
            else if (n >= 32 && n < 52) v = Wt[(i * 128 + k) * 20 + (n - 32)];
        }
        g_wsb[t] = (bf16_t)v;
    }

    if (blockIdx.x == 0) {
        int u = threadIdx.x;
        if (u < 40) phys_s[u] = u;
        __syncthreads();
        for (int i = 0; i < L; ++i) {
            if (u < 20) {
                int sa = phys_s[perm[i * 40 + ia[i * 20 + u]]];
                int sb = phys_s[perm[i * 40 + ib[i * 20 + u]]];
                pas[u] = sa; pbs[u] = sb;
                g_gtab[i * 32 + u]        = sa;
                g_gtab[192 + i * 20 + u]  = sb;
            } else if (u < 32) {
                g_gtab[i * 32 + u] = 0;          // benign pad slot (weights are 0 there)
            }
            __syncthreads();
            if (u < 20) {
                tmp_s[ia[i * 20 + u]] = pas[u];
                tmp_s[ib[i * 20 + u]] = pbs[u];
            }
            __syncthreads();
            if (u < 40) phys_s[u] = tmp_s[u];
            __syncthreads();
        }
        if (u < 40) g_gtab[312 + u] = phys_s[u];
    }
}

// ---------------------------------------------------------------------------
// prep_cte: fp32 ctx/te -> bf16 [B][256] concat (mm1 A-operand, k-major)
// ---------------------------------------------------------------------------
__global__ void prep_cte(const float* __restrict__ ctx, const float* __restrict__ te)
{
    using namespace cfg;
    size_t t = (size_t)blockIdx.x * blockDim.x + threadIdx.x;   // one float4 each
    size_t e = t * 4;
    size_t row = e >> 8;
    int j = (int)(e & 255);
    const float* src = (j < 128) ? &ctx[row * 128 + j] : &te[row * 128 + (j - 128)];
    float4 v = *(const float4*)src;
    bf16x4 bv;
    bv[0] = (bf16_t)v.x; bv[1] = (bf16_t)v.y; bv[2] = (bf16_t)v.z; bv[3] = (bf16_t)v.w;
    *(bf16x4*)&g_cte[row * 256 + j] = bv;
}

// [64 x 128] @ [128 x 128] + bias -> SiLU -> hout[64][136].
// Paired-column B-frags: frag slot c carries weight col (2c + nt&1), so each
// lane's two adjacent output cols pack into ONE ds_write_b32 (16 stores/wave
// instead of 32). LDS layout of hout stays natural.
// setprio(1) over the MFMA k-loop (T5): with 3 blocks/CU drifting out of
// phase, favor matrix-pipe waves over VALU/epilogue waves on the same SIMD.
__device__ __forceinline__ void mm_dense(
    const bf16_t* hin, const bf16_t* __restrict__ wl, const float* __restrict__ bias,
    bf16_t* hout, int q, int c, int r0, int c0)
{
    using namespace cfg;
    f32x4 acc[2][4] = {};
    __builtin_amdgcn_s_setprio(1);
    #pragma unroll
    for (int kt = 0; kt < 4; ++kt) {
        bf16x8 af0 = *(const bf16x8*)&hin[(r0 + c) * 136 + kt * 32 + q * 8];
        bf16x8 af1 = *(const bf16x8*)&hin[(r0 + 16 + c) * 136 + kt * 32 + q * 8];
        #pragma unroll
        for (int nt = 0; nt < 4; ++nt) {
            int an = c0 + (nt >> 1) * 32 + 2 * c + (nt & 1);
            bf16x8 bfr = *(const bf16x8*)&wl[kt * TILE + an * 32 + q * 8];
            acc[0][nt] = MFMA16(af0, bfr, acc[0][nt]);
            acc[1][nt] = MFMA16(af1, bfr, acc[1][nt]);
        }
    }
    __builtin_amdgcn_s_setprio(0);
    #pragma unroll
    for (int g = 0; g < 2; ++g) {
        int n0 = c0 + g * 32 + 2 * c;
        float bv0 = bias[n0], bv1 = bias[n0 + 1];
        #pragma unroll
        for (int mt = 0; mt < 2; ++mt)
            #pragma unroll
            for (int rr = 0; rr < 4; ++rr) {
                float v0 = silu_f(acc[mt][2 * g][rr] + bv0);
                float v1 = silu_f(acc[mt][2 * g + 1][rr] + bv1);
                union { bf16_t h[2]; uint32_t u32; } pk;
                pk.h[0] = (bf16_t)v0; pk.h[1] = (bf16_t)v1;
                *(uint32_t*)&hout[(r0 + mt * 16 + q * 4 + rr) * 136 + n0] = pk.u32;
            }
    }
}

__global__ __launch_bounds__(256, 3) void flow_main(
    const float* __restrict__ x,
    const float* __restrict__ b1, const float* __restrict__ b2, const float* __restrict__ b3,
    const float* __restrict__ bs, const float* __restrict__ bt,
    float* __restrict__ out)
{
    using namespace cfg;
    // LDS: 46464 B -> 3 blocks/CU.
    __shared__ __align__(16) char smem[46464];
    float*  z_s  = (float*)(smem);             // [64][40] f32   @0      (10240 B)
    bf16_t* hA   = (bf16_t*)(smem + 10240);    // [64][136] bf16 @10240  (17408 B)
    bf16_t* hB   = (bf16_t*)(smem + 27648);    // [64][136] bf16 @27648  (17408 B)
    int*    gtab = (int*)(smem + 45056);       // 352 ints       @45056  (1408 B)

    const int tid  = threadIdx.x;
    const int lane = tid & 63;
    const int w    = tid >> 6;
    const int q    = lane >> 4, c = lane & 15;
    const int wm   = w >> 1, wn = w & 1;
    const int r0   = wm * 32, c0 = wn * 64;
    const int rw   = w * 16;                   // st/epilogue row base (16 rows/wave)
    const int row0 = blockIdx.x * MB;

    for (int e = tid; e < 352; e += NTH) gtab[e] = g_gtab[e];
    for (int e = tid; e < MB * DIM; e += NTH)
        z_s[e] = x[(size_t)row0 * DIM + e];
    float ld[4] = {0.f, 0.f, 0.f, 0.f};
    __syncthreads();

    for (int i = 0; i < L; ++i) {
        const bf16_t* wlay = g_wsb + i * LSTR;
        const int* pa = gtab + i * 32;          // za read slots (padded to 32)
        const int* pb = gtab + 192 + i * 20;    // zb read/write slots

        // ---- mm1: [za | cte] @ W1t -> SiLU -> hA.  kt=0 gathers z_s inline.
        {
            f32x4 acc[2][4] = {};
            {   // K-tile 0 (z_a) — inline gather; k>=20 lanes read benign slot 0,
                // their weight columns are zero so the product contributes nothing.
                bf16x8 af0, af1;
                #pragma unroll
                for (int j = 0; j < 8; ++j) {
                    int slot = pa[q * 8 + j];
                    af0[j] = (bf16_t)z_s[(r0 + c) * DIM + slot];
                    af1[j] = (bf16_t)z_s[(r0 + 16 + c) * DIM + slot];
                }
                #pragma unroll
                for (int nt = 0; nt < 4; ++nt) {
                    int an = c0 + (nt >> 1) * 32 + 2 * c + (nt & 1);
                    bf16x8 bfr = *(const bf16x8*)&wlay[an * 32 + q * 8];
                    acc[0][nt] = MFMA16(af0, bfr, acc[0][nt]);
                    acc[1][nt] = MFMA16(af1, bfr, acc[1][nt]);
                }
            }
            __builtin_amdgcn_s_setprio(1);
            #pragma unroll
            for (int kt = 1; kt < 9; ++kt) {   // ctx/te from global bf16 (L1/L2-hot)
                bf16x8 af0 = *(const bf16x8*)&g_cte[(size_t)(row0 + r0 + c) * 256 + (kt - 1) * 32 + q * 8];
                bf16x8 af1 = *(const bf16x8*)&g_cte[(size_t)(row0 + r0 + 16 + c) * 256 + (kt - 1) * 32 + q * 8];
                #pragma unroll
                for (int nt = 0; nt < 4; ++nt) {
                    int an = c0 + (nt >> 1) * 32 + 2 * c + (nt & 1);
                    bf16x8 bfr = *(const bf16x8*)&wlay[kt * TILE + an * 32 + q * 8];
                    acc[0][nt] = MFMA16(af0, bfr, acc[0][nt]);
                    acc[1][nt] = MFMA16(af1, bfr, acc[1][nt]);
                }
            }
            __builtin_amdgcn_s_setprio(0);
            const float* bias = b1 + i * H;
            #pragma unroll
            for (int g = 0; g < 2; ++g) {
                int n0 = c0 + g * 32 + 2 * c;
                float bv0 = bias[n0], bv1 = bias[n0 + 1];
                #pragma unroll
                for (int mt = 0; mt < 2; ++mt)
                    #pragma unroll
                    for (int rr = 0; rr < 4; ++rr) {
                        float v0 = silu_f(acc[mt][2 * g][rr] + bv0);
                        float v1 = silu_f(acc[mt][2 * g + 1][rr] + bv1);
                        union { bf16_t h[2]; uint32_t u32; } pk;
                        pk.h[0] = (bf16_t)v0; pk.h[1] = (bf16_t)v1;
                        *(uint32_t*)&hA[(r0 + mt * 16 + q * 4 + rr) * 136 + n0] = pk.u32;
                    }
            }
        }
        __syncthreads();                       // hA ready

        mm_dense(hA, wlay + 9 * TILE,  b2 + i * H, hB, q, c, r0, c0);
        __syncthreads();                       // hB ready
        mm_dense(hB, wlay + 13 * TILE, b3 + i * H, hA, q, c, r0, c0);
        __syncthreads();                       // hA(h3) ready

        // ---- fused st + epilogue, fully in-register.
        // Each wave owns 16 rows x 64 cols: lane (q,c) ends up holding
        // s(j=c), s(j=16+c), t(j=c), t(j=16+c) for its 4 rows -> no LDS
        // round-trip for s/t; y_b overwrites z_s in place at slot pb[j].
        {
            const bf16_t* wst = wlay + 17 * TILE;
            f32x4 acc[4] = {};
            __builtin_amdgcn_s_setprio(1);
            #pragma unroll
            for (int kt = 0; kt < 4; ++kt) {
                bf16x8 af = *(const bf16x8*)&hA[(rw + c) * 136 + kt * 32 + q * 8];
                #pragma unroll
                for (int nt = 0; nt < 4; ++nt) {
                    bf16x8 bfr = *(const bf16x8*)&wst[kt * TILE + (nt * 16 + c) * 32 + q * 8];
                    acc[nt] = MFMA16(af, bfr, acc[nt]);
                }
            }
            __builtin_amdgcn_s_setprio(0);
            float bs0 = bs[i * AD + c];
            float bt0 = bt[i * AD + c];
            int   sl1 = pb[c];
            float bs1 = 0.f, bt1 = 0.f; int sl2 = 0;
            if (c < 4) { bs1 = bs[i * AD + 16 + c]; bt1 = bt[i * AD + 16 + c]; sl2 = pb[16 + c]; }
            #pragma unroll
            for (int rr = 0; rr < 4; ++rr) {
                int row = rw + q * 4 + rr;
                float s1 = fminf(fmaxf(acc[0][rr] + bs0, -2.f), 2.f);
                float y1 = z_s[row * DIM + sl1] * __expf(s1) + (acc[2][rr] + bt0);
                z_s[row * DIM + sl1] = y1;
                float ssum = s1;
                if (c < 4) {
                    float s2 = fminf(fmaxf(acc[1][rr] + bs1, -2.f), 2.f);
                    float y2 = z_s[row * DIM + sl2] * __expf(s2) + (acc[3][rr] + bt1);
                    z_s[row * DIM + sl2] = y2;
                    ssum += s2;
                }
                // row-sum of s across the 16 c-lanes (same q group)
                ssum += __shfl_xor(ssum, 1);
                ssum += __shfl_xor(ssum, 2);
                ssum += __shfl_xor(ssum, 4);
                ssum += __shfl_xor(ssum, 8);
                ld[rr] += ssum;
            }
        }
        __syncthreads();                       // z_s stable for next layer
    }

    // out gather through the final physical-slot map
    const int* fo = gtab + 312;
    for (int e = tid; e < MB * DIM; e += NTH) {
        int r = e / DIM, d = e - r * DIM;
        out[(size_t)row0 * DIM + e] = z_s[r * DIM + fo[d]];
    }
    if (c == 0) {
        #pragma unroll
        for (int rr = 0; rr < 4; ++rr)
            out[(size_t)B * DIM + row0 + rw + q * 4 + rr] = ld[rr];
    }
}

extern "C" void kernel_launch(void* const* d_in, const int* in_sizes, int n_in,
                              void* d_out, int out_size, void* d_ws, size_t ws_size,
                              hipStream_t stream) {
    using namespace cfg;
    const float* x   = (const float*)d_in[0];
    const float* ctx = (const float*)d_in[1];
    const float* te  = (const float*)d_in[2];
    const float* W1  = (const float*)d_in[3];
    const float* b1  = (const float*)d_in[4];
    const float* W2  = (const float*)d_in[5];
    const float* b2  = (const float*)d_in[6];
    const float* W3  = (const float*)d_in[7];
    const float* b3  = (const float*)d_in[8];
    const float* Ws_ = (const float*)d_in[9];
    const float* bs_ = (const float*)d_in[10];
    const float* Wt_ = (const float*)d_in[11];
    const float* bt_ = (const float*)d_in[12];
    const int* perm  = (const int*)d_in[13];
    const int* ia    = (const int*)d_in[14];
    const int* ib    = (const int*)d_in[15];

    float* out = (float*)d_out;

    prep_w<<<WTOT / 256, 256, 0, stream>>>(W1, W2, W3, Ws_, Wt_, perm, ia, ib);
    prep_cte<<<((size_t)B * 256 / 4) / 256, 256, 0, stream>>>(ctx, te);
    flow_main<<<B / MB, NTH, 0, stream>>>(x, b1, b2, b3, bs_, bt_, out);
}